// Round 1
// baseline (410.325 us; speedup 1.0000x reference)
//
#include <hip/hip_runtime.h>
#include <stdint.h>

#pragma clang fp contract(off)

#define FM 64
#define AC 9
#define N_ANCH (FM * FM * AC)            // 36864
#define PRE_NMS 1000
#define POST_NMS 300
#define SEL_CAP 1024
#define NT 1024

struct Scal {
    uint32_t prefix;
    uint32_t krem;
    uint32_t cnt;
    uint32_t pad;
    uint32_t wordPref[16];
    uint64_t keepW[16];
};

// LDS layout (bytes)
#define M_WORDS    (PRE_NMS * 16)                 // 16000 u64 = 128000 B
#define OFF_F      (M_WORDS * 8)                  // 128000
#define OFF_HIST   (OFF_F + 5 * SEL_CAP * 4)      // 148480
#define OFF_SCAL   (OFF_HIST + 256 * 4)           // 149504
#define SMEM_BYTES (OFF_SCAL + (int)sizeof(Scal)) // 149712

__device__ __forceinline__ uint32_t mono_key(float v) {
    uint32_t u = __float_as_uint(v);
    return (u & 0x80000000u) ? ~u : (u | 0x80000000u);
}

__device__ __forceinline__ float clip01(float x) {
    return fminf(fmaxf(x, 0.0f), 1.0f);
}

__global__ __launch_bounds__(NT) void roibbox_kernel(
    const float* __restrict__ deltas,   // (B, N, 4)
    const float* __restrict__ labels,   // (B, N)
    const float* __restrict__ anchors,  // (N, 4)
    float* __restrict__ out)            // (B, 300, 4)
{
    const int b    = blockIdx.x;
    const int t    = threadIdx.x;
    const int lane = t & 63;
    const int wave = t >> 6;

    extern __shared__ char smem_raw[];
    uint64_t* M    = (uint64_t*)(smem_raw);            // 128000 B (aliased by sel early)
    float*    ly1  = (float*)(smem_raw + OFF_F);
    float*    lx1  = ly1 + SEL_CAP;
    float*    ly2  = lx1 + SEL_CAP;
    float*    lx2  = ly2 + SEL_CAP;
    float*    lar  = lx2 + SEL_CAP;
    uint32_t* hist = (uint32_t*)(smem_raw + OFF_HIST);
    Scal*     sc   = (Scal*)(smem_raw + OFF_SCAL);
    uint64_t* sel  = M;                                // alias: used before M is needed

    const float* lab = labels + (size_t)b * N_ANCH;

    // ---------------- radix select: exact 1000th-largest key T ----------------
    if (t == 0) { sc->prefix = 0u; sc->krem = PRE_NMS; }
    for (int pass = 0; pass < 4; ++pass) {
        const int shift = 24 - 8 * pass;
        for (int i = t; i < 256; i += NT) hist[i] = 0u;
        __syncthreads();
        const uint32_t prefix = sc->prefix;
        const uint32_t himask = (pass == 0) ? 0u : (0xFFFFFFFFu << (shift + 8));
        for (int i = t; i < N_ANCH; i += NT) {
            uint32_t u = mono_key(lab[i]);
            if ((u & himask) == prefix)
                atomicAdd(&hist[(u >> shift) & 0xFFu], 1u);
        }
        __syncthreads();
        if (t == 0) {
            uint32_t krem = sc->krem, cum = 0u;
            for (int bin = 255; bin >= 0; --bin) {
                cum += hist[bin];
                if (cum >= krem) {
                    sc->krem   = krem - (cum - hist[bin]);
                    sc->prefix = prefix | ((uint32_t)bin << shift);
                    break;
                }
            }
        }
        __syncthreads();
    }
    const uint32_t T = sc->prefix;

    // ---------------- compact all keys >= T ----------------
    if (t == 0) sc->cnt = 0u;
    __syncthreads();
    for (int i = t; i < N_ANCH; i += NT) {
        uint32_t u = mono_key(lab[i]);
        if (u >= T) {
            uint32_t pos = atomicAdd(&sc->cnt, 1u);
            if (pos < SEL_CAP)
                sel[pos] = ((uint64_t)u << 32) | (uint64_t)(0xFFFFFFFFu - (uint32_t)i);
        }
    }
    __syncthreads();
    uint32_t cnt = sc->cnt;
    if (cnt > SEL_CAP) cnt = SEL_CAP;
    for (int i = (int)cnt + t; i < SEL_CAP; i += NT) sel[i] = 0ull;

    // ---------------- bitonic sort, descending, 1024 elems ----------------
    for (int k = 2; k <= SEL_CAP; k <<= 1) {
        for (int j = k >> 1; j > 0; j >>= 1) {
            __syncthreads();
            int ixj = t ^ j;
            if (ixj > t) {
                uint64_t a = sel[t], c = sel[ixj];
                bool desc = ((t & k) == 0);
                if (desc ? (a < c) : (a > c)) { sel[t] = c; sel[ixj] = a; }
            }
        }
    }
    __syncthreads();

    // ---------------- decode top-1000 boxes into SoA LDS ----------------
    if (t < PRE_NMS) {
        uint64_t s = sel[t];
        uint32_t idx = 0xFFFFFFFFu - (uint32_t)(s & 0xFFFFFFFFull);
        float4 d4 = *(const float4*)(deltas + ((size_t)b * N_ANCH + idx) * 4);
        float4 a4 = *(const float4*)(anchors + (size_t)idx * 4);
        float anc_h  = a4.z - a4.x;
        float anc_w  = a4.w - a4.y;
        float anc_cy = a4.x + 0.5f * anc_h;
        float anc_cx = a4.y + 0.5f * anc_w;
        float dy = d4.x * 0.1f, dx = d4.y * 0.1f;
        float dh = d4.z * 0.2f, dw = d4.w * 0.2f;
        float h  = expf(dh) * anc_h;
        float w  = expf(dw) * anc_w;
        float cy = dy * anc_h + anc_cy;
        float cx = dx * anc_w + anc_cx;
        float y1 = cy - 0.5f * h, x1 = cx - 0.5f * w;
        float y2 = cy + 0.5f * h, x2 = cx + 0.5f * w;
        ly1[t] = y1; lx1[t] = x1; ly2[t] = y2; lx2[t] = x2;
        lar[t] = (y2 - y1) * (x2 - x1);
    } else {
        ly1[t] = 0.f; lx1[t] = 0.f; ly2[t] = 0.f; lx2[t] = 0.f; lar[t] = 0.f;
    }
    __syncthreads();   // sel no longer needed; M may now overwrite it

    // ---------------- zero suppression matrix ----------------
    for (int i = t; i < M_WORDS; i += NT) M[i] = 0ull;
    __syncthreads();

    // ---------------- build suppression matrix (thread t = column j) ----------------
    {
        const float y1j = ly1[t], x1j = lx1[t], y2j = ly2[t], x2j = lx2[t], aj = lar[t];
        int rowmax = 64 * wave + 64;
        if (rowmax > PRE_NMS) rowmax = PRE_NMS;   // wave w: rows beyond its columns are all-zero
        for (int i = 0; i < rowmax; ++i) {
            float iy1 = fmaxf(ly1[i], y1j);
            float ix1 = fmaxf(lx1[i], x1j);
            float iy2 = fminf(ly2[i], y2j);
            float ix2 = fminf(lx2[i], x2j);
            float ih = iy2 - iy1; if (ih < 0.f) ih = 0.f;
            float iw = ix2 - ix1; if (iw < 0.f) iw = 0.f;
            float inter = ih * iw;
            float denom = lar[i] + aj - inter;
            if (denom < 1e-9f) denom = 1e-9f;
            float iou = inter / denom;            // IEEE divide: match numpy ref bits
            bool sup = (t > i) && (iou > 0.7f);
            uint64_t mask = __ballot(sup ? 1 : 0);
            if (lane == 0) M[(size_t)i * 16 + wave] = mask;
        }
    }
    __syncthreads();

    // ---------------- greedy NMS reduce (wave 0, barrier-free) ----------------
    if (wave == 0) {
        uint64_t remv = 0ull;            // lane l (l<16): suppression bits for j in [64l, 64l+64)
        const int myw = lane & 15;
        for (int w = 0; w < 16; ++w) {
            uint64_t cur = __shfl(remv, w);          // finalized state of word w
            const int base = w * 64;
            int nb = PRE_NMS - base; if (nb > 64) nb = 64;
            for (int bpos = 0; bpos < nb; ++bpos) {
                const int i = base + bpos;
                uint64_t ml = M[(size_t)i * 16 + myw];   // off critical path
                uint64_t mc = M[(size_t)i * 16 + w];
                uint64_t keepbit = (~(cur >> bpos)) & 1ull;
                uint64_t msk = 0ull - keepbit;           // all-ones if kept
                remv |= ml & msk;
                cur  |= mc & msk;
            }
        }
        if (lane < 16) {
            uint64_t kw = ~remv;
            if (myw == 15) kw &= (1ull << 40) - 1;       // bits >= 1000 invalid
            sc->keepW[lane] = kw;
        }
    }
    __syncthreads();

    // ---------------- ranks + output ----------------
    if (t == 0) {
        uint32_t acc = 0u;
        for (int w = 0; w < 16; ++w) {
            sc->wordPref[w] = acc;
            acc += (uint32_t)__popcll(sc->keepW[w]);
        }
    }
    float* ob = out + (size_t)b * (POST_NMS * 4);
    for (int i = t; i < POST_NMS * 4; i += NT) ob[i] = 0.0f;
    __syncthreads();

    if (t < PRE_NMS) {
        const int w = t >> 6, bpos = t & 63;
        uint64_t kw = sc->keepW[w];
        if ((kw >> bpos) & 1ull) {
            uint32_t rank = sc->wordPref[w] +
                            (uint32_t)__popcll(kw & ((1ull << bpos) - 1ull));
            if (rank < POST_NMS) {
                float* o = ob + (size_t)rank * 4;
                o[0] = clip01(ly1[t]);
                o[1] = clip01(lx1[t]);
                o[2] = clip01(ly2[t]);
                o[3] = clip01(lx2[t]);
            }
        }
    }
}

extern "C" void kernel_launch(void* const* d_in, const int* in_sizes, int n_in,
                              void* d_out, int out_size, void* d_ws, size_t ws_size,
                              hipStream_t stream) {
    const float* deltas  = (const float*)d_in[0];
    const float* labels  = (const float*)d_in[1];
    const float* anchors = (const float*)d_in[2];
    float* out = (float*)d_out;
    const int B = in_sizes[1] / N_ANCH;   // 16
    roibbox_kernel<<<B, NT, SMEM_BYTES, stream>>>(deltas, labels, anchors, out);
}

// Round 2
// 194.669 us; speedup vs baseline: 2.1078x; 2.1078x over previous
//
#include <hip/hip_runtime.h>
#include <stdint.h>

#pragma clang fp contract(off)

#define FM 64
#define AC 9
#define N_ANCH (FM * FM * AC)            // 36864
#define PRE_NMS 1000
#define POST_NMS 300
#define SEL_CAP 1024
#define NT 1024
#define KEYS_PT (N_ANCH / NT)            // 36 keys per thread
#define NWAVE 16
#define HSTRIDE 257                      // per-wave hist stride (bank-rotating pad)

struct Scal {
    uint32_t prefix;
    uint32_t krem;
    uint32_t cnt;
    uint32_t pad;
    uint32_t wordPref[16];
    uint64_t keepW[16];
};

// ws layout: [boxes SoA: B * 5 * 1024 floats][M: B * 1000 * 16 u64]
#define WS_BOX_FLOATS_PER_B (5 * SEL_CAP)
#define M_WORDS_PER_B (PRE_NMS * 16)     // 16000 u64

__device__ __forceinline__ uint32_t mono_key(float v) {
    uint32_t u = __float_as_uint(v);
    return (u & 0x80000000u) ? ~u : (u | 0x80000000u);
}

__device__ __forceinline__ float clip01(float x) {
    return fminf(fmaxf(x, 0.0f), 1.0f);
}

// ---------------------------------------------------------------------------
// K1: per-batch top-1000 (exact, jax tie-break), sort desc, decode -> ws SoA
// ---------------------------------------------------------------------------
__global__ __launch_bounds__(NT) void k1_select_decode(
    const float* __restrict__ deltas,   // (B, N, 4)
    const float* __restrict__ labels,   // (B, N)
    const float* __restrict__ anchors,  // (N, 4)
    float* __restrict__ wsBox)          // (B, 5, 1024)
{
    const int b    = blockIdx.x;
    const int t    = threadIdx.x;
    const int wave = t >> 6;

    __shared__ uint32_t wh[NWAVE * HSTRIDE];   // per-wave histograms
    __shared__ uint32_t ht[256];               // reduced histogram
    __shared__ uint64_t sel[SEL_CAP];
    __shared__ Scal sc;

    const float* lab = labels + (size_t)b * N_ANCH;

    // cache all keys in registers (coalesced loads)
    uint32_t keys[KEYS_PT];
#pragma unroll
    for (int r = 0; r < KEYS_PT; ++r)
        keys[r] = mono_key(lab[r * NT + t]);

    // ---- 4-pass radix select: exact 1000th-largest key T ----
    if (t == 0) { sc.prefix = 0u; sc.krem = PRE_NMS; }
    for (int pass = 0; pass < 4; ++pass) {
        const int shift = 24 - 8 * pass;
        for (int i = t; i < NWAVE * HSTRIDE; i += NT) wh[i] = 0u;
        __syncthreads();
        const uint32_t prefix = sc.prefix;
        const uint32_t himask = (pass == 0) ? 0u : (0xFFFFFFFFu << (shift + 8));
        uint32_t* myh = &wh[wave * HSTRIDE];
#pragma unroll
        for (int r = 0; r < KEYS_PT; ++r) {
            uint32_t u = keys[r];
            if ((u & himask) == prefix)
                atomicAdd(&myh[(u >> shift) & 0xFFu], 1u);
        }
        __syncthreads();
        if (t < 256) {
            uint32_t s = 0;
            for (int w = 0; w < NWAVE; ++w) s += wh[w * HSTRIDE + t];
            ht[t] = s;
        }
        __syncthreads();
        if (t == 0) {
            uint32_t krem = sc.krem, cum = 0u;
            for (int bin = 255; bin >= 0; --bin) {
                cum += ht[bin];
                if (cum >= krem) {
                    sc.krem   = krem - (cum - ht[bin]);
                    sc.prefix = prefix | ((uint32_t)bin << shift);
                    break;
                }
            }
        }
        __syncthreads();
    }
    const uint32_t T = sc.prefix;

    // ---- compact all keys >= T (guaranteed >= 1000 of them) ----
    if (t == 0) sc.cnt = 0u;
    __syncthreads();
#pragma unroll
    for (int r = 0; r < KEYS_PT; ++r) {
        uint32_t u = keys[r];
        if (u >= T) {
            uint32_t pos = atomicAdd(&sc.cnt, 1u);
            if (pos < SEL_CAP)
                sel[pos] = ((uint64_t)u << 32) |
                           (uint64_t)(0xFFFFFFFFu - (uint32_t)(r * NT + t));
        }
    }
    __syncthreads();
    uint32_t cnt = sc.cnt;
    if (cnt > SEL_CAP) cnt = SEL_CAP;
    for (int i = (int)cnt + t; i < SEL_CAP; i += NT) sel[i] = 0ull;

    // ---- bitonic sort descending (value desc, index asc == jax top_k) ----
    for (int k = 2; k <= SEL_CAP; k <<= 1) {
        for (int j = k >> 1; j > 0; j >>= 1) {
            __syncthreads();
            int ixj = t ^ j;
            if (ixj > t) {
                uint64_t a = sel[t], c = sel[ixj];
                bool desc = ((t & k) == 0);
                if (desc ? (a < c) : (a > c)) { sel[t] = c; sel[ixj] = a; }
            }
        }
    }
    __syncthreads();

    // ---- decode top-1000 boxes -> ws SoA ----
    float* wb = wsBox + (size_t)b * WS_BOX_FLOATS_PER_B;
    if (t < PRE_NMS) {
        uint64_t s = sel[t];
        uint32_t idx = 0xFFFFFFFFu - (uint32_t)(s & 0xFFFFFFFFull);
        float4 d4 = *(const float4*)(deltas + ((size_t)b * N_ANCH + idx) * 4);
        float4 a4 = *(const float4*)(anchors + (size_t)idx * 4);
        float anc_h  = a4.z - a4.x;
        float anc_w  = a4.w - a4.y;
        float anc_cy = a4.x + 0.5f * anc_h;
        float anc_cx = a4.y + 0.5f * anc_w;
        float dy = d4.x * 0.1f, dx = d4.y * 0.1f;
        float dh = d4.z * 0.2f, dw = d4.w * 0.2f;
        float h  = expf(dh) * anc_h;
        float w  = expf(dw) * anc_w;
        float cy = dy * anc_h + anc_cy;
        float cx = dx * anc_w + anc_cx;
        float y1 = cy - 0.5f * h, x1 = cx - 0.5f * w;
        float y2 = cy + 0.5f * h, x2 = cx + 0.5f * w;
        wb[t]             = y1;
        wb[SEL_CAP + t]   = x1;
        wb[2*SEL_CAP + t] = y2;
        wb[3*SEL_CAP + t] = x2;
        wb[4*SEL_CAP + t] = (y2 - y1) * (x2 - x1);
    } else {
        wb[t] = 0.f; wb[SEL_CAP + t] = 0.f; wb[2*SEL_CAP + t] = 0.f;
        wb[3*SEL_CAP + t] = 0.f; wb[4*SEL_CAP + t] = 0.f;
    }
}

// ---------------------------------------------------------------------------
// K2: suppression matrix. block (cb, b) -> columns [64cb,64cb+64) x rows
//     [0, 64(cb+1)). 256 blocks total. lane = column, wave strides rows.
// ---------------------------------------------------------------------------
__global__ __launch_bounds__(NT) void k2_iou_matrix(
    const float* __restrict__ wsBox,
    uint64_t* __restrict__ wsM)
{
    const int cb   = blockIdx.x;
    const int b    = blockIdx.y;
    const int t    = threadIdx.x;
    const int lane = t & 63;
    const int wave = t >> 6;

    __shared__ float s[5 * SEL_CAP];
    const float* base = wsBox + (size_t)b * WS_BOX_FLOATS_PER_B;
    for (int i = t; i < 5 * SEL_CAP; i += NT) s[i] = base[i];
    __syncthreads();

    float* ly1 = s;
    float* lx1 = s + SEL_CAP;
    float* ly2 = s + 2 * SEL_CAP;
    float* lx2 = s + 3 * SEL_CAP;
    float* lar = s + 4 * SEL_CAP;

    const int j = cb * 64 + lane;
    const float y1j = ly1[j], x1j = lx1[j], y2j = ly2[j], x2j = lx2[j], aj = lar[j];

    int rowmax = 64 * (cb + 1);
    if (rowmax > PRE_NMS) rowmax = PRE_NMS;
    uint64_t* Mb = wsM + (size_t)b * M_WORDS_PER_B;

    for (int i = wave; i < rowmax; i += NWAVE) {
        float iy1 = fmaxf(ly1[i], y1j);
        float ix1 = fmaxf(lx1[i], x1j);
        float iy2 = fminf(ly2[i], y2j);
        float ix2 = fminf(lx2[i], x2j);
        float ih = iy2 - iy1; if (ih < 0.f) ih = 0.f;
        float iw = ix2 - ix1; if (iw < 0.f) iw = 0.f;
        float inter = ih * iw;
        float denom = lar[i] + aj - inter;
        if (denom < 1e-9f) denom = 1e-9f;
        float iou = inter / denom;            // IEEE divide: match numpy bits
        bool sup = (j > i) && (iou > 0.7f);
        uint64_t mask = __ballot(sup ? 1 : 0);
        if (lane == 0) Mb[(size_t)i * 16 + cb] = mask;
    }
}

// ---------------------------------------------------------------------------
// K3: greedy NMS reduce + output. one block per batch.
// ---------------------------------------------------------------------------
__global__ __launch_bounds__(NT) void k3_reduce_out(
    const float* __restrict__ wsBox,
    const uint64_t* __restrict__ wsM,
    float* __restrict__ out)
{
    const int b    = blockIdx.x;
    const int t    = threadIdx.x;
    const int lane = t & 63;
    const int wave = t >> 6;

    extern __shared__ char smem_raw[];
    uint64_t* M  = (uint64_t*)smem_raw;                          // 16000 u64
    Scal*     sc = (Scal*)(smem_raw + M_WORDS_PER_B * 8);

    // load M, masking words the column-blocks never wrote (all-zero rows)
    const uint64_t* Mg = wsM + (size_t)b * M_WORDS_PER_B;
    for (int idx = t; idx < M_WORDS_PER_B; idx += NT) {
        int row = idx >> 4, w = idx & 15;
        uint64_t v = Mg[idx];
        M[idx] = (row < 64 * w + 64) ? v : 0ull;
    }
    __syncthreads();

    // greedy reduce on wave 0, barrier-free (exact sequential semantics)
    if (wave == 0) {
        uint64_t remv = 0ull;          // lane l (<16): suppression word l
        const int myw = lane & 15;
        for (int w = 0; w < 16; ++w) {
            uint64_t cur = __shfl(remv, w);
            const int base = w * 64;
            int nb = PRE_NMS - base; if (nb > 64) nb = 64;
            for (int bpos = 0; bpos < nb; ++bpos) {
                const int i = base + bpos;
                uint64_t ml = M[(size_t)i * 16 + myw];
                uint64_t mc = M[(size_t)i * 16 + w];
                uint64_t keepbit = (~(cur >> bpos)) & 1ull;
                uint64_t msk = 0ull - keepbit;
                remv |= ml & msk;
                cur  |= mc & msk;
            }
        }
        if (lane < 16) {
            uint64_t kw = ~remv;
            if (myw == 15) kw &= (1ull << 40) - 1;   // bits >= 1000 invalid
            sc->keepW[lane] = kw;
        }
    }
    __syncthreads();

    if (t == 0) {
        uint32_t acc = 0u;
        for (int w = 0; w < 16; ++w) {
            sc->wordPref[w] = acc;
            acc += (uint32_t)__popcll(sc->keepW[w]);
        }
    }
    float* ob = out + (size_t)b * (POST_NMS * 4);
    for (int i = t; i < POST_NMS * 4; i += NT) ob[i] = 0.0f;
    __syncthreads();

    if (t < PRE_NMS) {
        const int w = t >> 6, bpos = t & 63;
        uint64_t kw = sc->keepW[w];
        if ((kw >> bpos) & 1ull) {
            uint32_t rank = sc->wordPref[w] +
                            (uint32_t)__popcll(kw & ((1ull << bpos) - 1ull));
            if (rank < POST_NMS) {
                const float* wb = wsBox + (size_t)b * WS_BOX_FLOATS_PER_B;
                float* o = ob + (size_t)rank * 4;
                o[0] = clip01(wb[t]);
                o[1] = clip01(wb[SEL_CAP + t]);
                o[2] = clip01(wb[2*SEL_CAP + t]);
                o[3] = clip01(wb[3*SEL_CAP + t]);
            }
        }
    }
}

extern "C" void kernel_launch(void* const* d_in, const int* in_sizes, int n_in,
                              void* d_out, int out_size, void* d_ws, size_t ws_size,
                              hipStream_t stream) {
    const float* deltas  = (const float*)d_in[0];
    const float* labels  = (const float*)d_in[1];
    const float* anchors = (const float*)d_in[2];
    float* out = (float*)d_out;
    const int B = in_sizes[1] / N_ANCH;   // 16

    float*    wsBox = (float*)d_ws;
    uint64_t* wsM   = (uint64_t*)((char*)d_ws +
                                  (size_t)B * WS_BOX_FLOATS_PER_B * sizeof(float));

    k1_select_decode<<<B, NT, 0, stream>>>(deltas, labels, anchors, wsBox);
    k2_iou_matrix<<<dim3(16, B), NT, 0, stream>>>(wsBox, wsM);
    const int k3_smem = M_WORDS_PER_B * 8 + (int)sizeof(Scal);
    k3_reduce_out<<<B, NT, k3_smem, stream>>>(wsBox, wsM, out);
}

// Round 3
// 166.100 us; speedup vs baseline: 2.4704x; 1.1720x over previous
//
#include <hip/hip_runtime.h>
#include <stdint.h>

#pragma clang fp contract(off)

#define FM 64
#define AC 9
#define N_ANCH (FM * FM * AC)            // 36864
#define PRE_NMS 1000
#define POST_NMS 300
#define SEL_CAP 1024
#define NT 1024
#define KEYS_PT (N_ANCH / NT)            // 36 keys per thread
#define NWAVE 16

// K1 histogram: 4096 bins, 4 lane-spread copies
#define NBIN 4096
#define NCOPY 4
#define HSTR (NBIN + 8)                  // u32 stride per copy (bank rotate)

struct K1S {
    uint32_t krem;
    uint32_t threshA;
    uint32_t threshBin;
    uint32_t crossWave;
    uint32_t crossAbove;
    uint32_t cnt;
    uint32_t pad0, pad1;
    uint32_t wavesum[NWAVE];
};

#define K1_HIST_BYTES (NCOPY * HSTR * 4)           // 65664
#define K1_SEL_OFF    K1_HIST_BYTES
#define K1_SC_OFF     (K1_SEL_OFF + SEL_CAP * 8)   // 73856
#define K1_SMEM       (K1_SC_OFF + (int)sizeof(K1S))

// ws layout: [boxes SoA: B * 5 * 1024 floats][M: B * 1000 * 16 u64]
#define WS_BOX_FLOATS_PER_B (5 * SEL_CAP)
#define M_WORDS_PER_B (PRE_NMS * 16)     // 16000 u64

struct K3S { uint32_t wordPref[16]; uint64_t keepW[16]; };
#define K3_SMEM (M_WORDS_PER_B * 8 + (int)sizeof(K3S))

__device__ __forceinline__ uint32_t mono_key(float v) {
    uint32_t u = __float_as_uint(v);
    return (u & 0x80000000u) ? ~u : (u | 0x80000000u);
}

__device__ __forceinline__ float clip01(float x) {
    return fminf(fmaxf(x, 0.0f), 1.0f);
}

__device__ __forceinline__ uint64_t bcast64(uint64_t v, int srclane) {
    uint32_t lo = (uint32_t)v, hi = (uint32_t)(v >> 32);
    lo = __builtin_amdgcn_readlane(lo, srclane);
    hi = __builtin_amdgcn_readlane(hi, srclane);
    return ((uint64_t)hi << 32) | (uint64_t)lo;
}

// ---------------------------------------------------------------------------
// K1: per-batch exact top-1000 (2-pass 12-bit radix select + bitonic sort),
//     decode -> ws SoA. One block per batch.
// ---------------------------------------------------------------------------
__global__ __launch_bounds__(NT) void k1_select_decode(
    const float* __restrict__ deltas,   // (B, N, 4)
    const float* __restrict__ labels,   // (B, N)
    const float* __restrict__ anchors,  // (N, 4)
    float* __restrict__ wsBox)          // (B, 5, 1024)
{
    const int b    = blockIdx.x;
    const int t    = threadIdx.x;
    const int lane = t & 63;
    const int wave = t >> 6;

    extern __shared__ char sm[];
    uint32_t* hist = (uint32_t*)sm;
    uint64_t* sel  = (uint64_t*)(sm + K1_SEL_OFF);
    K1S*      sc   = (K1S*)(sm + K1_SC_OFF);

    const float* lab = labels + (size_t)b * N_ANCH;
    const int copy = lane >> 4;              // 4 copies, 16 lanes each

    if (t == 0) sc->krem = PRE_NMS;

    for (int pass = 0; pass < 2; ++pass) {
        for (int i = t; i < NCOPY * HSTR; i += NT) hist[i] = 0u;
        __syncthreads();
        const uint32_t threshA = sc->threshA;   // valid only in pass 1
#pragma unroll
        for (int r = 0; r < KEYS_PT; ++r) {
            uint32_t u = mono_key(lab[r * NT + t]);
            if (pass == 0) {
                atomicAdd(&hist[copy * HSTR + (u >> 20)], 1u);
            } else if ((u >> 20) == threshA) {
                atomicAdd(&hist[copy * HSTR + ((u >> 8) & 0xFFFu)], 1u);
            }
        }
        __syncthreads();

        // reduce copies -> totals in copy 0; thread t owns bins 4t..4t+3
        const int b0 = 4 * t;
        uint32_t h0 = 0, h1 = 0, h2 = 0, h3 = 0;
        for (int c = 0; c < NCOPY; ++c) {
            int base = c * HSTR + b0;
            h0 += hist[base]; h1 += hist[base + 1];
            h2 += hist[base + 2]; h3 += hist[base + 3];
        }
        hist[b0] = h0; hist[b0 + 1] = h1; hist[b0 + 2] = h2; hist[b0 + 3] = h3;
        uint32_t wt = h0 + h1 + h2 + h3;
        wt += __shfl_xor(wt, 32); wt += __shfl_xor(wt, 16);
        wt += __shfl_xor(wt, 8);  wt += __shfl_xor(wt, 4);
        wt += __shfl_xor(wt, 2);  wt += __shfl_xor(wt, 1);
        if (lane == 0) sc->wavesum[wave] = wt;
        __syncthreads();

        // level 1: which 256-bin wave-chunk contains the K-th largest
        if (wave == 0) {
            const uint32_t K = sc->krem;
            uint32_t wsl = (lane < NWAVE) ? sc->wavesum[lane] : 0u;
            uint32_t above = 0;
            for (int w2 = lane + 1; w2 < NWAVE; ++w2) above += sc->wavesum[w2];
            bool cross = (lane < NWAVE) && (above < K) && (above + wsl >= K);
            if (cross) { sc->crossWave = (uint32_t)lane; sc->crossAbove = above; }
        }
        __syncthreads();

        // level 2: resolve bin inside chunk (lane -> 4 bins, suffix scan)
        if (wave == 0) {
            const uint32_t K = sc->krem;
            const int wb = (int)sc->crossWave;
            const uint32_t above0 = sc->crossAbove;
            const int base = 256 * wb + 4 * lane;
            uint32_t g0 = hist[base], g1 = hist[base + 1];
            uint32_t g2 = hist[base + 2], g3 = hist[base + 3];
            uint32_t q = g0 + g1 + g2 + g3;
            uint32_t s = q, o;
            o = __shfl_down(s, 1);  if (lane < 63) s += o;
            o = __shfl_down(s, 2);  if (lane < 62) s += o;
            o = __shfl_down(s, 4);  if (lane < 60) s += o;
            o = __shfl_down(s, 8);  if (lane < 56) s += o;
            o = __shfl_down(s, 16); if (lane < 48) s += o;
            o = __shfl_down(s, 32); if (lane < 32) s += o;
            uint32_t aboveL = above0 + (s - q);
            bool cross = (aboveL < K) && (aboveL + q >= K);
            if (cross) {
                uint32_t a = aboveL; int tb;
                if (a + g3 >= K) tb = base + 3;
                else { a += g3;
                    if (a + g2 >= K) tb = base + 2;
                    else { a += g2;
                        if (a + g1 >= K) tb = base + 1;
                        else { a += g1; tb = base; } } }
                sc->threshBin = (uint32_t)tb;
                if (pass == 0) { sc->threshA = (uint32_t)tb; sc->krem = K - a; }
            }
        }
        __syncthreads();
    }

    const uint32_t thresh24 = (sc->threshA << 12) | sc->threshBin;

    // ---- compact all keys with 24-bit prefix >= thresh24 (~1000 + ties) ----
    if (t == 0) sc->cnt = 0u;
    __syncthreads();
#pragma unroll
    for (int r = 0; r < KEYS_PT; ++r) {
        const int i = r * NT + t;
        uint32_t u = mono_key(lab[i]);
        if ((u >> 8) >= thresh24) {
            uint32_t pos = atomicAdd(&sc->cnt, 1u);
            if (pos < SEL_CAP)
                sel[pos] = ((uint64_t)u << 32) |
                           (uint64_t)(0xFFFFFFFFu - (uint32_t)i);
        }
    }
    __syncthreads();
    uint32_t cnt = sc->cnt;
    if (cnt > SEL_CAP) cnt = SEL_CAP;
    for (int i = (int)cnt + t; i < SEL_CAP; i += NT) sel[i] = 0ull;

    // ---- bitonic sort descending (value desc, index asc == jax top_k) ----
    for (int k = 2; k <= SEL_CAP; k <<= 1) {
        for (int j = k >> 1; j > 0; j >>= 1) {
            __syncthreads();
            int ixj = t ^ j;
            if (ixj > t) {
                uint64_t a = sel[t], c = sel[ixj];
                bool desc = ((t & k) == 0);
                if (desc ? (a < c) : (a > c)) { sel[t] = c; sel[ixj] = a; }
            }
        }
    }
    __syncthreads();

    // ---- decode top-1000 boxes -> ws SoA ----
    float* wb = wsBox + (size_t)b * WS_BOX_FLOATS_PER_B;
    if (t < PRE_NMS) {
        uint64_t s = sel[t];
        uint32_t idx = 0xFFFFFFFFu - (uint32_t)(s & 0xFFFFFFFFull);
        float4 d4 = *(const float4*)(deltas + ((size_t)b * N_ANCH + idx) * 4);
        float4 a4 = *(const float4*)(anchors + (size_t)idx * 4);
        float anc_h  = a4.z - a4.x;
        float anc_w  = a4.w - a4.y;
        float anc_cy = a4.x + 0.5f * anc_h;
        float anc_cx = a4.y + 0.5f * anc_w;
        float dy = d4.x * 0.1f, dx = d4.y * 0.1f;
        float dh = d4.z * 0.2f, dw = d4.w * 0.2f;
        float h  = expf(dh) * anc_h;
        float w  = expf(dw) * anc_w;
        float cy = dy * anc_h + anc_cy;
        float cx = dx * anc_w + anc_cx;
        float y1 = cy - 0.5f * h, x1 = cx - 0.5f * w;
        float y2 = cy + 0.5f * h, x2 = cx + 0.5f * w;
        wb[t]             = y1;
        wb[SEL_CAP + t]   = x1;
        wb[2*SEL_CAP + t] = y2;
        wb[3*SEL_CAP + t] = x2;
        wb[4*SEL_CAP + t] = (y2 - y1) * (x2 - x1);
    } else {
        wb[t] = 0.f; wb[SEL_CAP + t] = 0.f; wb[2*SEL_CAP + t] = 0.f;
        wb[3*SEL_CAP + t] = 0.f; wb[4*SEL_CAP + t] = 0.f;
    }
}

// ---------------------------------------------------------------------------
// K2: suppression matrix. block (cb, b) -> columns [64cb,64cb+64) x rows
//     [0, 64(cb+1)). 256 blocks total. lane = column, wave strides rows.
// ---------------------------------------------------------------------------
__global__ __launch_bounds__(NT) void k2_iou_matrix(
    const float* __restrict__ wsBox,
    uint64_t* __restrict__ wsM)
{
    const int cb   = blockIdx.x;
    const int b    = blockIdx.y;
    const int t    = threadIdx.x;
    const int lane = t & 63;
    const int wave = t >> 6;

    __shared__ float s[5 * SEL_CAP];
    const float* base = wsBox + (size_t)b * WS_BOX_FLOATS_PER_B;
    for (int i = t; i < 5 * SEL_CAP; i += NT) s[i] = base[i];
    __syncthreads();

    float* ly1 = s;
    float* lx1 = s + SEL_CAP;
    float* ly2 = s + 2 * SEL_CAP;
    float* lx2 = s + 3 * SEL_CAP;
    float* lar = s + 4 * SEL_CAP;

    const int j = cb * 64 + lane;
    const float y1j = ly1[j], x1j = lx1[j], y2j = ly2[j], x2j = lx2[j], aj = lar[j];

    int rowmax = 64 * (cb + 1);
    if (rowmax > PRE_NMS) rowmax = PRE_NMS;
    uint64_t* Mb = wsM + (size_t)b * M_WORDS_PER_B;

    for (int i = wave; i < rowmax; i += NWAVE) {
        float iy1 = fmaxf(ly1[i], y1j);
        float ix1 = fmaxf(lx1[i], x1j);
        float iy2 = fminf(ly2[i], y2j);
        float ix2 = fminf(lx2[i], x2j);
        float ih = iy2 - iy1; if (ih < 0.f) ih = 0.f;
        float iw = ix2 - ix1; if (iw < 0.f) iw = 0.f;
        float inter = ih * iw;
        float denom = lar[i] + aj - inter;
        if (denom < 1e-9f) denom = 1e-9f;
        float iou = inter / denom;            // IEEE divide: match numpy bits
        bool sup = (j > i) && (iou > 0.7f);
        uint64_t mask = __ballot(sup ? 1 : 0);
        if (lane == 0) Mb[(size_t)i * 16 + cb] = mask;
    }
}

// ---------------------------------------------------------------------------
// K3: greedy NMS reduce + output. one block per batch. Scalarized chain:
//     current word broadcast via readlane (SGPR chain), 1 ds_read_b64 / row.
// ---------------------------------------------------------------------------
__global__ __launch_bounds__(NT) void k3_reduce_out(
    const float* __restrict__ wsBox,
    const uint64_t* __restrict__ wsM,
    float* __restrict__ out)
{
    const int b    = blockIdx.x;
    const int t    = threadIdx.x;
    const int lane = t & 63;
    const int wave = t >> 6;

    extern __shared__ char sm[];
    uint64_t* M  = (uint64_t*)sm;                          // 16000 u64
    K3S*      sc = (K3S*)(sm + M_WORDS_PER_B * 8);

    // load M, masking words the column-blocks never wrote (poisoned ws!)
    const uint64_t* Mg = wsM + (size_t)b * M_WORDS_PER_B;
    for (int idx = t; idx < M_WORDS_PER_B; idx += NT) {
        int row = idx >> 4, w = idx & 15;
        uint64_t v = Mg[idx];
        M[idx] = (row < 64 * w + 64) ? v : 0ull;
    }
    __syncthreads();

    if (wave == 0) {
        uint64_t remv = 0ull;            // lane l (<16): suppression word l
        const int myw = lane & 15;
        for (int w = 0; w < 16; ++w) {
            uint64_t cur = bcast64(remv, w);    // finalized word w (uniform)
            const int nch = (w == 15) ? 5 : 8;  // word 15: only 40 valid bits
            for (int c = 0; c < nch; ++c) {
                uint64_t ml[8];
                const int i0 = w * 64 + c * 8;
#pragma unroll
                for (int k = 0; k < 8; ++k)
                    ml[k] = M[(size_t)(i0 + k) * 16 + myw];
#pragma unroll
                for (int k = 0; k < 8; ++k) {
                    const int bpos = c * 8 + k;
                    uint64_t mc   = bcast64(ml[k], w);   // row's word w (uniform)
                    uint64_t keep = (~(cur >> bpos)) & 1ull;
                    uint64_t msk  = 0ull - keep;
                    remv |= ml[k] & msk;
                    cur  |= mc & msk;
                }
            }
        }
        if (lane < 16) {
            uint64_t kw = ~remv;
            if (myw == 15) kw &= (1ull << 40) - 1ull;    // bits >= 1000 invalid
            sc->keepW[lane] = kw;
        }
    }
    __syncthreads();

    if (t == 0) {
        uint32_t acc = 0u;
        for (int w = 0; w < 16; ++w) {
            sc->wordPref[w] = acc;
            acc += (uint32_t)__popcll(sc->keepW[w]);
        }
    }
    float* ob = out + (size_t)b * (POST_NMS * 4);
    for (int i = t; i < POST_NMS * 4; i += NT) ob[i] = 0.0f;
    __syncthreads();

    if (t < PRE_NMS) {
        const int w = t >> 6, bpos = t & 63;
        uint64_t kw = sc->keepW[w];
        if ((kw >> bpos) & 1ull) {
            uint32_t rank = sc->wordPref[w] +
                            (uint32_t)__popcll(kw & ((1ull << bpos) - 1ull));
            if (rank < POST_NMS) {
                const float* wb = wsBox + (size_t)b * WS_BOX_FLOATS_PER_B;
                float* o = ob + (size_t)rank * 4;
                o[0] = clip01(wb[t]);
                o[1] = clip01(wb[SEL_CAP + t]);
                o[2] = clip01(wb[2*SEL_CAP + t]);
                o[3] = clip01(wb[3*SEL_CAP + t]);
            }
        }
    }
}

extern "C" void kernel_launch(void* const* d_in, const int* in_sizes, int n_in,
                              void* d_out, int out_size, void* d_ws, size_t ws_size,
                              hipStream_t stream) {
    const float* deltas  = (const float*)d_in[0];
    const float* labels  = (const float*)d_in[1];
    const float* anchors = (const float*)d_in[2];
    float* out = (float*)d_out;
    const int B = in_sizes[1] / N_ANCH;   // 16

    float*    wsBox = (float*)d_ws;
    uint64_t* wsM   = (uint64_t*)((char*)d_ws +
                                  (size_t)B * WS_BOX_FLOATS_PER_B * sizeof(float));

    k1_select_decode<<<B, NT, K1_SMEM, stream>>>(deltas, labels, anchors, wsBox);
    k2_iou_matrix<<<dim3(16, B), NT, 0, stream>>>(wsBox, wsM);
    k3_reduce_out<<<B, NT, K3_SMEM, stream>>>(wsBox, wsM, out);
}